// Round 5
// baseline (403.437 us; speedup 1.0000x reference)
//
#include <hip/hip_runtime.h>
#include <stdint.h>
#include <stddef.h>

// Problem constants (DINOv2 self-attention)
#define SQ     1370              // sequence length
#define SP     1408              // padded V^T row stride (covers 22 j-tiles of 64)
#define NJ     22                // ceil(SQ/64) key tiles
#define NBATCH 8
#define NHEADS 16
#define DH     64                // head dim
#define DM     1024              // model dim
#define MROWS  (NBATCH * SQ)     // 10960 flattened rows

typedef _Float16 f16;
typedef __attribute__((ext_vector_type(8))) _Float16 f16x8;
typedef __attribute__((ext_vector_type(4))) _Float16 f16x4;
typedef __attribute__((ext_vector_type(4))) float    f32x4;

#define MFMA_16x16x32_F16(a, b, c) __builtin_amdgcn_mfma_f32_16x16x32_f16((a), (b), (c), 0, 0, 0)

// Async global->LDS DMA, 16 B per lane. LDS dest must be wave-uniform base +
// lane*16 (hardware constraint); the global side is an ordinary per-lane addr.
__device__ __forceinline__ void load_lds_16(const f16* g, f16* l) {
    __builtin_amdgcn_global_load_lds(
        (const __attribute__((address_space(1))) void*)g,
        (__attribute__((address_space(3))) void*)l, 16, 0, 0);
}

// ---------------------------------------------------------------------------
// Kernel 0: fp32 -> f16 convert (hs + the three weight matrices).
// ---------------------------------------------------------------------------
__global__ __launch_bounds__(256) void cvt_kernel(
    const float* __restrict__ s0, const float* __restrict__ s1,
    const float* __restrict__ s2, const float* __restrict__ s3,
    f16* __restrict__ d0, f16* __restrict__ d1,
    f16* __restrict__ d2, f16* __restrict__ d3,
    int n0, int n1, int n2, int n3)     // counts in float4 units
{
    const float* s; f16* d; int n;
    switch (blockIdx.y) {
        case 0:  s = s0; d = d0; n = n0; break;
        case 1:  s = s1; d = d1; n = n1; break;
        case 2:  s = s2; d = d2; n = n2; break;
        default: s = s3; d = d3; n = n3; break;
    }
    const int stride = gridDim.x * blockDim.x;
    for (int i = blockIdx.x * blockDim.x + threadIdx.x; i < n; i += stride) {
        const float4 v = ((const float4*)s)[i];
        ((f16x4*)d)[i] = (f16x4){(f16)v.x, (f16)v.y, (f16)v.z, (f16)v.w};
    }
}

// ---------------------------------------------------------------------------
// Kernel 1: QKV projection GEMM, pure f16 inputs, BK=64 (16 K-steps -> half
// the barrier drains of BK=32). Tile 128x128, 4 waves.
// LDS tiles [128][64] f16 unpadded; chunk-XOR swizzle (phys = logical ^
// (row&7)) applied on the GLOBAL source so fragment reads are 2-way bank-
// aliased (free) while the DMA dest stays lane-linear.
// Grid (n=8, m=86, z=3): consecutive blocks share the A m-tile (L2 locality).
// Q,K written [B*H, S, DH]; V written transposed [B*H, DH, SP].
// ---------------------------------------------------------------------------
__global__ __launch_bounds__(256) void qkv_gemm_kernel(
    const f16* __restrict__ A,        // [MROWS][DM] f16
    const f16* __restrict__ Wq16, const f16* __restrict__ Wk16,
    const f16* __restrict__ Wv16,
    const float* __restrict__ bq, const float* __restrict__ bk,
    const float* __restrict__ bv,
    f16* __restrict__ Qo, f16* __restrict__ Ko, f16* __restrict__ Vto)
{
    __shared__ f16 As[128 * 64];
    __shared__ f16 Bs[128 * 64];

    const f16* W; const float* bias;
    if (blockIdx.z == 0)      { W = Wq16; bias = bq; }
    else if (blockIdx.z == 1) { W = Wk16; bias = bk; }
    else                      { W = Wv16; bias = bv; }

    const int n0   = blockIdx.x * 128;
    const int m0   = blockIdx.y * 128;
    const int t    = threadIdx.x;
    const int lane = t & 63;
    const int wid  = t >> 6;
    const int wm   = (wid >> 1) * 64;
    const int wn   = (wid & 1) * 64;
    const int lr   = lane & 15;
    const int quad = lane >> 4;

    f32x4 acc[4][4];
#pragma unroll
    for (int i = 0; i < 4; i++)
#pragma unroll
        for (int j = 0; j < 4; j++) acc[i][j] = (f32x4){0.f, 0.f, 0.f, 0.f};

    // Staging: 1024 16B-chunks per tile; thread t handles c = t + 256*i.
    // row = c>>3 (8 chunks/row), phys chunk = c&7, logical = phys ^ (row&7).
    const f16* asrc[4]; const f16* bsrc[4];
#pragma unroll
    for (int i = 0; i < 4; i++) {
        const int c   = t + 256 * i;
        const int row = c >> 3;
        const int lc  = ((c & 7) ^ (row & 7)) * 8;
        int am = m0 + row; if (am >= MROWS) am = MROWS - 1;   // clamp tail
        asrc[i] = A + (size_t)am * DM + lc;
        bsrc[i] = W + (size_t)(n0 + row) * DM + lc;
    }

    for (int k0 = 0; k0 < DM; k0 += 64) {
        __syncthreads();                         // prev compute reads done
#pragma unroll
        for (int i = 0; i < 4; i++)
            load_lds_16(asrc[i] + k0, As + (t + 256 * i) * 8);
#pragma unroll
        for (int i = 0; i < 4; i++)
            load_lds_16(bsrc[i] + k0, Bs + (t + 256 * i) * 8);
        __syncthreads();                         // vmcnt drained before barrier

#pragma unroll
        for (int kk = 0; kk < 2; kk++) {
            // Fragment phys chunk (per lane): (kk*4+quad) ^ (lr&7)
            const int fph = ((kk * 4 + quad) ^ (lr & 7)) * 8;
            f16x8 af[4], bf[4];
#pragma unroll
            for (int i = 0; i < 4; i++) {
                af[i] = *(const f16x8*)&As[(wm + i * 16 + lr) * 64 + fph];
                bf[i] = *(const f16x8*)&Bs[(wn + i * 16 + lr) * 64 + fph];
            }
#pragma unroll
            for (int i = 0; i < 4; i++)
#pragma unroll
                for (int j = 0; j < 4; j++)
                    acc[i][j] = MFMA_16x16x32_F16(af[i], bf[j], acc[i][j]);
        }
    }

    // Epilogue. C/D layout: row = quad*4+reg, col = lane&15 (m89-verified).
#pragma unroll
    for (int j = 0; j < 4; j++) {
        const int n  = n0 + wn + j * 16 + lr;
        const float bv_ = bias[n];
        const int h = n >> 6, d = n & 63;
#pragma unroll
        for (int i = 0; i < 4; i++) {
#pragma unroll
            for (int r = 0; r < 4; r++) {
                const int m = m0 + wm + i * 16 + quad * 4 + r;
                if (m < MROWS) {
                    const int b = m / SQ, s = m % SQ;
                    const f16 val = (f16)(acc[i][j][r] + bv_);
                    if (blockIdx.z == 2) {
                        Vto[((size_t)((b * NHEADS + h) * DH + d)) * SP + s] = val;
                    } else {
                        f16* outp = (blockIdx.z == 0) ? Qo : Ko;
                        outp[(((size_t)(b * NHEADS + h)) * SQ + s) * DH + d] = val;
                    }
                }
            }
        }
    }
}

// ---------------------------------------------------------------------------
// Kernel 2: flash attention, LDS-staged K/V, double-buffered, 40 KB LDS
// (4 blocks/CU). Wave owns 32 q-rows. Scores are computed PRE-SHIFTED by
// initializing the QK accumulator to -mrun, so the common path applies exp2
// with no subtraction; rescale runs only when the tile max exceeds mrun
// (wave-uniform branch, rare after early tiles). P round-trips through a
// halved wave-private LDS region in two passes (in-order per-wave DS pipe).
// ---------------------------------------------------------------------------
__global__ __launch_bounds__(256) void attn_kernel(
    const f16* __restrict__ Q,   // [B*H, SQ, DH]
    const f16* __restrict__ K,   // [B*H, SQ, DH]
    const f16* __restrict__ Vt,  // [B*H, DH, SP]
    float* __restrict__ out)     // [B, SQ, DM]
{
    __shared__ f16 Kt[2][64 * 64];    // 16 KB
    __shared__ f16 Vs[2][64 * 64];    // 16 KB
    __shared__ f16 Pl[4][16 * 64];    // 8 KB: per-wave 16-row P, two passes

    const int q0   = blockIdx.x * 128;
    const int bh   = blockIdx.y;
    const int b    = bh >> 4;
    const int h    = bh & 15;
    const int t    = threadIdx.x;
    const int lane = t & 63;
    const int wid  = t >> 6;
    const int lr   = lane & 15;
    const int quad = lane >> 4;

    const f16* Qb = Q  + (size_t)bh * SQ * DH;
    const f16* Kb = K  + (size_t)bh * SQ * DH;
    const f16* Vb = Vt + (size_t)bh * DH * SP;

    // Q A-fragments for 2 row-blocks, pre-scaled by 0.125*log2(e)
    const f16 qs = (f16)0.1803368801f;
    f16x8 qf[2][2];
#pragma unroll
    for (int rb = 0; rb < 2; rb++) {
        int qrow = q0 + wid * 32 + rb * 16 + lr;
        if (qrow >= SQ) qrow = SQ - 1;
        qf[rb][0] = *(const f16x8*)(Qb + (size_t)qrow * DH + quad * 8) * qs;
        qf[rb][1] = *(const f16x8*)(Qb + (size_t)qrow * DH + 32 + quad * 8) * qs;
    }

    const f16x8 ones = (f16x8){(f16)1.f, (f16)1.f, (f16)1.f, (f16)1.f,
                               (f16)1.f, (f16)1.f, (f16)1.f, (f16)1.f};

    f32x4 o[2][4];
#pragma unroll
    for (int rb = 0; rb < 2; rb++)
#pragma unroll
        for (int d = 0; d < 4; d++) o[rb][d] = (f32x4){0.f, 0.f, 0.f, 0.f};
    f32x4 lsum[2] = {(f32x4){0.f, 0.f, 0.f, 0.f}, (f32x4){0.f, 0.f, 0.f, 0.f}};
    float mrun = 0.f;   // valid by shift-invariance; P<=1 guaranteed below

    // Staging: thread t handles phys chunk t&7 of row t>>3 (rows 0..31);
    // second issue covers rows 32..63. Logical chunk = phys ^ (row&7).
    const int srow = t >> 3;
    const int slc  = ((t & 7) ^ (srow & 7)) * 8;
    const f16* ksrc = Kb + (size_t)srow * DH + slc;
    const f16* vsrc = Vb + (size_t)srow * SP + slc;

    // Fragment-read phys chunks (per lane): logical quad / 4+quad
    const int fp0 = ((quad)     ^ (lr & 7)) * 8;
    const int fp1 = ((quad + 4) ^ (lr & 7)) * 8;

#define STAGE(bufi, j0)                                                        \
    do {                                                                       \
        load_lds_16(ksrc + (size_t)(j0) * DH, &Kt[bufi][0] + t * 8);           \
        load_lds_16(ksrc + (size_t)((j0) + 32) * DH, &Kt[bufi][2048] + t * 8); \
        load_lds_16(vsrc + (j0), &Vs[bufi][0] + t * 8);                        \
        load_lds_16(vsrc + 32 * SP + (j0), &Vs[bufi][2048] + t * 8);           \
    } while (0)

    STAGE(0, 0);
    int buf = 0;

    for (int jt = 0; jt < NJ; ++jt) {
        const int j0 = jt * 64;
        __syncthreads();                       // buf staged (vmcnt drains here)
        if (jt + 1 < NJ) STAGE(buf ^ 1, j0 + 64);

        // K B-fragments (shared by both row-blocks)
        f16x8 kf[4][2];
#pragma unroll
        for (int nb = 0; nb < 4; nb++) {
            kf[nb][0] = *(const f16x8*)&Kt[buf][(nb * 16 + lr) * 64 + fp0];
            kf[nb][1] = *(const f16x8*)&Kt[buf][(nb * 16 + lr) * 64 + fp1];
        }

        // Pre-shifted scores: d = s - mrun (C init = -mrun), C-layout
        const float nm = -mrun;
        f32x4 d4[2][4];
#pragma unroll
        for (int rb = 0; rb < 2; rb++)
#pragma unroll
            for (int nb = 0; nb < 4; nb++) {
                f32x4 acc = (f32x4){nm, nm, nm, nm};
                acc = MFMA_16x16x32_F16(qf[rb][0], kf[nb][0], acc);
                acc = MFMA_16x16x32_F16(qf[rb][1], kf[nb][1], acc);
                d4[rb][nb] = acc;
            }
        if (jt == NJ - 1) {                    // mask tail keys
#pragma unroll
            for (int nb = 0; nb < 4; nb++)
                if (j0 + nb * 16 + lr >= SQ)
#pragma unroll
                    for (int rb = 0; rb < 2; rb++)
#pragma unroll
                        for (int r = 0; r < 4; r++)
                            d4[rb][nb][r] = -__builtin_inff();
        }

        // Wave-shared tile max of d (d <= 0 means no rescale needed)
        float Md = d4[0][0][0];
#pragma unroll
        for (int rb = 0; rb < 2; rb++)
#pragma unroll
            for (int nb = 0; nb < 4; nb++)
#pragma unroll
                for (int r = 0; r < 4; r++) Md = fmaxf(Md, d4[rb][nb][r]);
#pragma unroll
        for (int off = 1; off < 64; off <<= 1)
            Md = fmaxf(Md, __shfl_xor(Md, off, 64));

        if (Md > 0.f) {                        // rare after early tiles
            const float al = __builtin_amdgcn_exp2f(-Md);
            mrun += Md;
#pragma unroll
            for (int rb = 0; rb < 2; rb++) {
#pragma unroll
                for (int d = 0; d < 4; d++)
#pragma unroll
                    for (int r = 0; r < 4; r++) o[rb][d][r] *= al;
#pragma unroll
                for (int r = 0; r < 4; r++) lsum[rb][r] *= al;
#pragma unroll
                for (int nb = 0; nb < 4; nb++)
#pragma unroll
                    for (int r = 0; r < 4; r++) d4[rb][nb][r] -= Md;
            }
        }

        // V^T B-fragments (shared by both row-blocks and both P passes)
        f16x8 vf[4][2];
#pragma unroll
        for (int db = 0; db < 4; db++) {
            vf[db][0] = *(const f16x8*)&Vs[buf][(db * 16 + lr) * 64 + fp0];
            vf[db][1] = *(const f16x8*)&Vs[buf][(db * 16 + lr) * 64 + fp1];
        }

        // P round-trip: two wave-private passes over the halved Pl region.
        const int rbk = lr >> 2;
        const int pb0 = ((((quad >> 1) + rbk) & 3) << 4) + ((quad & 1) << 3);
        const int pb1 = (((2 + (quad >> 1) + rbk) & 3) << 4) + ((quad & 1) << 3);
#pragma unroll
        for (int rb = 0; rb < 2; rb++) {
            // write P = exp2(d) (d <= 0), rotation-swizzled
#pragma unroll
            for (int nb = 0; nb < 4; nb++) {
                const int pb = ((nb + quad) & 3) << 4;
#pragma unroll
                for (int r = 0; r < 4; r++)
                    Pl[wid][(quad * 4 + r) * 64 + pb + lr] =
                        (f16)__builtin_amdgcn_exp2f(d4[rb][nb][r]);
            }
            const f16x8 pf0 = *(const f16x8*)&Pl[wid][lr * 64 + pb0];
            const f16x8 pf1 = *(const f16x8*)&Pl[wid][lr * 64 + pb1];
            lsum[rb] = MFMA_16x16x32_F16(pf0, ones, lsum[rb]);
            lsum[rb] = MFMA_16x16x32_F16(pf1, ones, lsum[rb]);
#pragma unroll
            for (int db = 0; db < 4; db++) {
                o[rb][db] = MFMA_16x16x32_F16(pf0, vf[db][0], o[rb][db]);
                o[rb][db] = MFMA_16x16x32_F16(pf1, vf[db][1], o[rb][db]);
            }
        }
        buf ^= 1;
    }
#undef STAGE

    // Epilogue: normalize, write fp32 [B, S, H*DH]
#pragma unroll
    for (int rb = 0; rb < 2; rb++)
#pragma unroll
        for (int r = 0; r < 4; r++) {
            const int srow_q = q0 + wid * 32 + rb * 16 + quad * 4 + r;
            if (srow_q < SQ) {
                const float inv = 1.0f / lsum[rb][r];
#pragma unroll
                for (int db = 0; db < 4; db++)
                    out[((size_t)(b * SQ + srow_q)) * DM + h * DH + db * 16 + lr] =
                        o[rb][db][r] * inv;
            }
        }
}

// ---------------------------------------------------------------------------
extern "C" void kernel_launch(void* const* d_in, const int* in_sizes, int n_in,
                              void* d_out, int out_size, void* d_ws, size_t ws_size,
                              hipStream_t stream) {
    const float* hs = (const float*)d_in[0];
    const float* Wq = (const float*)d_in[1];
    const float* bq = (const float*)d_in[2];
    const float* Wk = (const float*)d_in[3];
    const float* bk = (const float*)d_in[4];
    const float* Wv = (const float*)d_in[5];
    const float* bv = (const float*)d_in[6];
    float* out = (float*)d_out;

    const size_t qk_elems = (size_t)NBATCH * NHEADS * SQ * DH;
    const size_t vt_elems = (size_t)NBATCH * NHEADS * DH * SP;
    const size_t hs_elems = (size_t)MROWS * DM;
    const size_t w_elems  = (size_t)DM * DM;
    f16* Qw   = (f16*)d_ws;
    f16* Kw   = Qw + qk_elems;
    f16* Vtw  = Kw + qk_elems;
    f16* hs16 = Vtw + vt_elems;
    f16* Wq16 = hs16 + hs_elems;
    f16* Wk16 = Wq16 + w_elems;
    f16* Wv16 = Wk16 + w_elems;

    dim3 gcvt(512, 4);
    cvt_kernel<<<gcvt, 256, 0, stream>>>(hs, Wq, Wk, Wv,
                                         hs16, Wq16, Wk16, Wv16,
                                         (int)(hs_elems / 4), (int)(w_elems / 4),
                                         (int)(w_elems / 4), (int)(w_elems / 4));

    dim3 ggemm(DM / 128, (MROWS + 127) / 128, 3);   // (8, 86, 3)
    qkv_gemm_kernel<<<ggemm, 256, 0, stream>>>(hs16, Wq16, Wk16, Wv16,
                                               bq, bk, bv, Qw, Kw, Vtw);

    dim3 gattn((SQ + 127) / 128, NBATCH * NHEADS);  // (11, 128)
    attn_kernel<<<gattn, 256, 0, stream>>>(Qw, Kw, Vtw, out);
}

// Round 6
// 387.766 us; speedup vs baseline: 1.0404x; 1.0404x over previous
//
#include <hip/hip_runtime.h>
#include <stdint.h>
#include <stddef.h>

// Problem constants (DINOv2 self-attention)
#define SQ     1370              // sequence length
#define SP     1408              // padded V^T row stride (covers 22 j-tiles of 64)
#define NJ     22                // ceil(SQ/64) key tiles
#define NBATCH 8
#define NHEADS 16
#define DH     64                // head dim
#define DM     1024              // model dim
#define MROWS  (NBATCH * SQ)     // 10960 flattened rows
#define MT     86                // m-tiles (128 rows each)

typedef _Float16 f16;
typedef __attribute__((ext_vector_type(8))) _Float16 f16x8;
typedef __attribute__((ext_vector_type(4))) _Float16 f16x4;
typedef __attribute__((ext_vector_type(4))) float    f32x4;

#define MFMA_16x16x32_F16(a, b, c) __builtin_amdgcn_mfma_f32_16x16x32_f16((a), (b), (c), 0, 0, 0)

// Async global->LDS DMA, 16 B per lane. LDS dest must be wave-uniform base +
// lane*16 (hardware constraint); the global side is an ordinary per-lane addr.
__device__ __forceinline__ void load_lds_16(const f16* g, f16* l) {
    __builtin_amdgcn_global_load_lds(
        (const __attribute__((address_space(1))) void*)g,
        (__attribute__((address_space(3))) void*)l, 16, 0, 0);
}

// ---------------------------------------------------------------------------
// Kernel 0: fp32 -> f16 convert (hs + the three weight matrices).
// ---------------------------------------------------------------------------
__global__ __launch_bounds__(256) void cvt_kernel(
    const float* __restrict__ s0, const float* __restrict__ s1,
    const float* __restrict__ s2, const float* __restrict__ s3,
    f16* __restrict__ d0, f16* __restrict__ d1,
    f16* __restrict__ d2, f16* __restrict__ d3,
    int n0, int n1, int n2, int n3)     // counts in float4 units
{
    const float* s; f16* d; int n;
    switch (blockIdx.y) {
        case 0:  s = s0; d = d0; n = n0; break;
        case 1:  s = s1; d = d1; n = n1; break;
        case 2:  s = s2; d = d2; n = n2; break;
        default: s = s3; d = d3; n = n3; break;
    }
    const int stride = gridDim.x * blockDim.x;
    for (int i = blockIdx.x * blockDim.x + threadIdx.x; i < n; i += stride) {
        const float4 v = ((const float4*)s)[i];
        ((f16x4*)d)[i] = (f16x4){(f16)v.x, (f16)v.y, (f16)v.z, (f16)v.w};
    }
}

// ---------------------------------------------------------------------------
// Kernel 1: QKV projection GEMM, pure f16 inputs, BK=64, tile 128x128.
// XCD-aware remap (1-D grid, 2064 blocks): xcd = L&7 (round-robin CP
// mapping), g = L>>3 orders each XCD's work z-outer -> m-slice -> n-inner.
// Each XCD owns a contiguous ~10.75-m-tile slice of A; per-z working set
// (W_z 2 MB + A tile 256 KB) fits the 4 MB per-XCD L2, so W stays resident
// and A is fetched ~once per z. Predicted fetch ~115 MB (was 270 MB).
// LDS chunk-XOR swizzle as before (conflict-free, DMA dest lane-linear).
// Q,K written [B*H, S, DH]; V written transposed [B*H, DH, SP].
// ---------------------------------------------------------------------------
__global__ __launch_bounds__(256) void qkv_gemm_kernel(
    const f16* __restrict__ A,        // [MROWS][DM] f16
    const f16* __restrict__ Wq16, const f16* __restrict__ Wk16,
    const f16* __restrict__ Wv16,
    const float* __restrict__ bq, const float* __restrict__ bk,
    const float* __restrict__ bv,
    f16* __restrict__ Qo, f16* __restrict__ Ko, f16* __restrict__ Vto)
{
    __shared__ f16 As[128 * 64];
    __shared__ f16 Bs[128 * 64];

    // --- XCD-aware work decomposition ---
    const int L = blockIdx.x;         // 0..2063
    const int x = L & 7;              // XCD (round-robin dispatch assumption)
    const int g = L >> 3;             // per-XCD sequence 0..257
    const int z = g / MT;             // 0..2  (z outer)
    const int w = x * MT + (g % MT);  // within-z work id 0..687, m-contig per XCD
    const int m0 = (w >> 3) * 128;
    const int n0 = (w & 7) * 128;

    const f16* W; const float* bias;
    if (z == 0)      { W = Wq16; bias = bq; }
    else if (z == 1) { W = Wk16; bias = bk; }
    else             { W = Wv16; bias = bv; }

    const int t    = threadIdx.x;
    const int lane = t & 63;
    const int wid  = t >> 6;
    const int wm   = (wid >> 1) * 64;
    const int wn   = (wid & 1) * 64;
    const int lr   = lane & 15;
    const int quad = lane >> 4;

    f32x4 acc[4][4];
#pragma unroll
    for (int i = 0; i < 4; i++)
#pragma unroll
        for (int j = 0; j < 4; j++) acc[i][j] = (f32x4){0.f, 0.f, 0.f, 0.f};

    // Staging: 1024 16B-chunks per tile; thread t handles c = t + 256*i.
    // row = c>>3 (8 chunks/row), phys chunk = c&7, logical = phys ^ (row&7).
    const f16* asrc[4]; const f16* bsrc[4];
#pragma unroll
    for (int i = 0; i < 4; i++) {
        const int c   = t + 256 * i;
        const int row = c >> 3;
        const int lc  = ((c & 7) ^ (row & 7)) * 8;
        int am = m0 + row; if (am >= MROWS) am = MROWS - 1;   // clamp tail
        asrc[i] = A + (size_t)am * DM + lc;
        bsrc[i] = W + (size_t)(n0 + row) * DM + lc;
    }

    for (int k0 = 0; k0 < DM; k0 += 64) {
        __syncthreads();                         // prev compute reads done
#pragma unroll
        for (int i = 0; i < 4; i++)
            load_lds_16(asrc[i] + k0, As + (t + 256 * i) * 8);
#pragma unroll
        for (int i = 0; i < 4; i++)
            load_lds_16(bsrc[i] + k0, Bs + (t + 256 * i) * 8);
        __syncthreads();                         // vmcnt drained before barrier

#pragma unroll
        for (int kk = 0; kk < 2; kk++) {
            // Fragment phys chunk (per lane): (kk*4+quad) ^ (lr&7)
            const int fph = ((kk * 4 + quad) ^ (lr & 7)) * 8;
            f16x8 af[4], bf[4];
#pragma unroll
            for (int i = 0; i < 4; i++) {
                af[i] = *(const f16x8*)&As[(wm + i * 16 + lr) * 64 + fph];
                bf[i] = *(const f16x8*)&Bs[(wn + i * 16 + lr) * 64 + fph];
            }
#pragma unroll
            for (int i = 0; i < 4; i++)
#pragma unroll
                for (int j = 0; j < 4; j++)
                    acc[i][j] = MFMA_16x16x32_F16(af[i], bf[j], acc[i][j]);
        }
    }

    // Epilogue. C/D layout: row = quad*4+reg, col = lane&15 (m89-verified).
#pragma unroll
    for (int j = 0; j < 4; j++) {
        const int n  = n0 + wn + j * 16 + lr;
        const float bv_ = bias[n];
        const int h = n >> 6, d = n & 63;
#pragma unroll
        for (int i = 0; i < 4; i++) {
#pragma unroll
            for (int r = 0; r < 4; r++) {
                const int m = m0 + wm + i * 16 + quad * 4 + r;
                if (m < MROWS) {
                    const int b = m / SQ, s = m % SQ;
                    const f16 val = (f16)(acc[i][j][r] + bv_);
                    if (z == 2) {
                        Vto[((size_t)((b * NHEADS + h) * DH + d)) * SP + s] = val;
                    } else {
                        f16* outp = (z == 0) ? Qo : Ko;
                        outp[(((size_t)(b * NHEADS + h)) * SQ + s) * DH + d] = val;
                    }
                }
            }
        }
    }
}

// ---------------------------------------------------------------------------
// Kernel 2: flash attention, LDS-staged K/V, double-buffered, 40 KB LDS.
// Wave owns 32 q-rows. Scores computed PRE-SHIFTED (C init = -mrun); rescale
// only when tile max exceeds mrun (wave-uniform, rare). P round-trips through
// a halved wave-private LDS region in two passes (in-order per-wave DS pipe).
// ---------------------------------------------------------------------------
__global__ __launch_bounds__(256) void attn_kernel(
    const f16* __restrict__ Q,   // [B*H, SQ, DH]
    const f16* __restrict__ K,   // [B*H, SQ, DH]
    const f16* __restrict__ Vt,  // [B*H, DH, SP]
    float* __restrict__ out)     // [B, SQ, DM]
{
    __shared__ f16 Kt[2][64 * 64];    // 16 KB
    __shared__ f16 Vs[2][64 * 64];    // 16 KB
    __shared__ f16 Pl[4][16 * 64];    // 8 KB: per-wave 16-row P, two passes

    const int q0   = blockIdx.x * 128;
    const int bh   = blockIdx.y;
    const int b    = bh >> 4;
    const int h    = bh & 15;
    const int t    = threadIdx.x;
    const int lane = t & 63;
    const int wid  = t >> 6;
    const int lr   = lane & 15;
    const int quad = lane >> 4;

    const f16* Qb = Q  + (size_t)bh * SQ * DH;
    const f16* Kb = K  + (size_t)bh * SQ * DH;
    const f16* Vb = Vt + (size_t)bh * DH * SP;

    // Q A-fragments for 2 row-blocks, pre-scaled by 0.125*log2(e)
    const f16 qs = (f16)0.1803368801f;
    f16x8 qf[2][2];
#pragma unroll
    for (int rb = 0; rb < 2; rb++) {
        int qrow = q0 + wid * 32 + rb * 16 + lr;
        if (qrow >= SQ) qrow = SQ - 1;
        qf[rb][0] = *(const f16x8*)(Qb + (size_t)qrow * DH + quad * 8) * qs;
        qf[rb][1] = *(const f16x8*)(Qb + (size_t)qrow * DH + 32 + quad * 8) * qs;
    }

    const f16x8 ones = (f16x8){(f16)1.f, (f16)1.f, (f16)1.f, (f16)1.f,
                               (f16)1.f, (f16)1.f, (f16)1.f, (f16)1.f};

    f32x4 o[2][4];
#pragma unroll
    for (int rb = 0; rb < 2; rb++)
#pragma unroll
        for (int d = 0; d < 4; d++) o[rb][d] = (f32x4){0.f, 0.f, 0.f, 0.f};
    f32x4 lsum[2] = {(f32x4){0.f, 0.f, 0.f, 0.f}, (f32x4){0.f, 0.f, 0.f, 0.f}};
    float mrun = 0.f;   // valid by shift-invariance; P<=1 guaranteed below

    // Staging: thread t handles phys chunk t&7 of row t>>3 (rows 0..31);
    // second issue covers rows 32..63. Logical chunk = phys ^ (row&7).
    const int srow = t >> 3;
    const int slc  = ((t & 7) ^ (srow & 7)) * 8;
    const f16* ksrc = Kb + (size_t)srow * DH + slc;
    const f16* vsrc = Vb + (size_t)srow * SP + slc;

    // Fragment-read phys chunks (per lane): logical quad / 4+quad
    const int fp0 = ((quad)     ^ (lr & 7)) * 8;
    const int fp1 = ((quad + 4) ^ (lr & 7)) * 8;

#define STAGE(bufi, j0)                                                        \
    do {                                                                       \
        load_lds_16(ksrc + (size_t)(j0) * DH, &Kt[bufi][0] + t * 8);           \
        load_lds_16(ksrc + (size_t)((j0) + 32) * DH, &Kt[bufi][2048] + t * 8); \
        load_lds_16(vsrc + (j0), &Vs[bufi][0] + t * 8);                        \
        load_lds_16(vsrc + 32 * SP + (j0), &Vs[bufi][2048] + t * 8);           \
    } while (0)

    STAGE(0, 0);
    int buf = 0;

    for (int jt = 0; jt < NJ; ++jt) {
        const int j0 = jt * 64;
        __syncthreads();                       // buf staged (vmcnt drains here)
        if (jt + 1 < NJ) STAGE(buf ^ 1, j0 + 64);

        // K B-fragments (shared by both row-blocks)
        f16x8 kf[4][2];
#pragma unroll
        for (int nb = 0; nb < 4; nb++) {
            kf[nb][0] = *(const f16x8*)&Kt[buf][(nb * 16 + lr) * 64 + fp0];
            kf[nb][1] = *(const f16x8*)&Kt[buf][(nb * 16 + lr) * 64 + fp1];
        }

        // Pre-shifted scores: d = s - mrun (C init = -mrun), C-layout
        const float nm = -mrun;
        f32x4 d4[2][4];
#pragma unroll
        for (int rb = 0; rb < 2; rb++)
#pragma unroll
            for (int nb = 0; nb < 4; nb++) {
                f32x4 acc = (f32x4){nm, nm, nm, nm};
                acc = MFMA_16x16x32_F16(qf[rb][0], kf[nb][0], acc);
                acc = MFMA_16x16x32_F16(qf[rb][1], kf[nb][1], acc);
                d4[rb][nb] = acc;
            }
        if (jt == NJ - 1) {                    // mask tail keys
#pragma unroll
            for (int nb = 0; nb < 4; nb++)
                if (j0 + nb * 16 + lr >= SQ)
#pragma unroll
                    for (int rb = 0; rb < 2; rb++)
#pragma unroll
                        for (int r = 0; r < 4; r++)
                            d4[rb][nb][r] = -__builtin_inff();
        }

        // Wave-shared tile max of d (d <= 0 means no rescale needed)
        float Md = d4[0][0][0];
#pragma unroll
        for (int rb = 0; rb < 2; rb++)
#pragma unroll
            for (int nb = 0; nb < 4; nb++)
#pragma unroll
                for (int r = 0; r < 4; r++) Md = fmaxf(Md, d4[rb][nb][r]);
#pragma unroll
        for (int off = 1; off < 64; off <<= 1)
            Md = fmaxf(Md, __shfl_xor(Md, off, 64));

        if (Md > 0.f) {                        // rare after early tiles
            const float al = __builtin_amdgcn_exp2f(-Md);
            mrun += Md;
#pragma unroll
            for (int rb = 0; rb < 2; rb++) {
#pragma unroll
                for (int d = 0; d < 4; d++)
#pragma unroll
                    for (int r = 0; r < 4; r++) o[rb][d][r] *= al;
#pragma unroll
                for (int r = 0; r < 4; r++) lsum[rb][r] *= al;
#pragma unroll
                for (int nb = 0; nb < 4; nb++)
#pragma unroll
                    for (int r = 0; r < 4; r++) d4[rb][nb][r] -= Md;
            }
        }

        // V^T B-fragments (shared by both row-blocks and both P passes)
        f16x8 vf[4][2];
#pragma unroll
        for (int db = 0; db < 4; db++) {
            vf[db][0] = *(const f16x8*)&Vs[buf][(db * 16 + lr) * 64 + fp0];
            vf[db][1] = *(const f16x8*)&Vs[buf][(db * 16 + lr) * 64 + fp1];
        }

        // P round-trip: two wave-private passes over the halved Pl region.
        const int rbk = lr >> 2;
        const int pb0 = ((((quad >> 1) + rbk) & 3) << 4) + ((quad & 1) << 3);
        const int pb1 = (((2 + (quad >> 1) + rbk) & 3) << 4) + ((quad & 1) << 3);
#pragma unroll
        for (int rb = 0; rb < 2; rb++) {
            // write P = exp2(d) (d <= 0), rotation-swizzled
#pragma unroll
            for (int nb = 0; nb < 4; nb++) {
                const int pb = ((nb + quad) & 3) << 4;
#pragma unroll
                for (int r = 0; r < 4; r++)
                    Pl[wid][(quad * 4 + r) * 64 + pb + lr] =
                        (f16)__builtin_amdgcn_exp2f(d4[rb][nb][r]);
            }
            const f16x8 pf0 = *(const f16x8*)&Pl[wid][lr * 64 + pb0];
            const f16x8 pf1 = *(const f16x8*)&Pl[wid][lr * 64 + pb1];
            lsum[rb] = MFMA_16x16x32_F16(pf0, ones, lsum[rb]);
            lsum[rb] = MFMA_16x16x32_F16(pf1, ones, lsum[rb]);
#pragma unroll
            for (int db = 0; db < 4; db++) {
                o[rb][db] = MFMA_16x16x32_F16(pf0, vf[db][0], o[rb][db]);
                o[rb][db] = MFMA_16x16x32_F16(pf1, vf[db][1], o[rb][db]);
            }
        }
        buf ^= 1;
    }
#undef STAGE

    // Epilogue: normalize, write fp32 [B, S, H*DH]
#pragma unroll
    for (int rb = 0; rb < 2; rb++)
#pragma unroll
        for (int r = 0; r < 4; r++) {
            const int srow_q = q0 + wid * 32 + rb * 16 + quad * 4 + r;
            if (srow_q < SQ) {
                const float inv = 1.0f / lsum[rb][r];
#pragma unroll
                for (int db = 0; db < 4; db++)
                    out[((size_t)(b * SQ + srow_q)) * DM + h * DH + db * 16 + lr] =
                        o[rb][db][r] * inv;
            }
        }
}

// ---------------------------------------------------------------------------
extern "C" void kernel_launch(void* const* d_in, const int* in_sizes, int n_in,
                              void* d_out, int out_size, void* d_ws, size_t ws_size,
                              hipStream_t stream) {
    const float* hs = (const float*)d_in[0];
    const float* Wq = (const float*)d_in[1];
    const float* bq = (const float*)d_in[2];
    const float* Wk = (const float*)d_in[3];
    const float* bk = (const float*)d_in[4];
    const float* Wv = (const float*)d_in[5];
    const float* bv = (const float*)d_in[6];
    float* out = (float*)d_out;

    const size_t qk_elems = (size_t)NBATCH * NHEADS * SQ * DH;
    const size_t vt_elems = (size_t)NBATCH * NHEADS * DH * SP;
    const size_t hs_elems = (size_t)MROWS * DM;
    const size_t w_elems  = (size_t)DM * DM;
    f16* Qw   = (f16*)d_ws;
    f16* Kw   = Qw + qk_elems;
    f16* Vtw  = Kw + qk_elems;
    f16* hs16 = Vtw + vt_elems;
    f16* Wq16 = hs16 + hs_elems;
    f16* Wk16 = Wq16 + w_elems;
    f16* Wv16 = Wk16 + w_elems;

    dim3 gcvt(512, 4);
    cvt_kernel<<<gcvt, 256, 0, stream>>>(hs, Wq, Wk, Wv,
                                         hs16, Wq16, Wk16, Wv16,
                                         (int)(hs_elems / 4), (int)(w_elems / 4),
                                         (int)(w_elems / 4), (int)(w_elems / 4));

    // XCD-aware 1-D grid: 86 m-tiles x 8 n-tiles x 3 z = 2064 blocks
    qkv_gemm_kernel<<<dim3(MT * 8 * 3), 256, 0, stream>>>(
        hs16, Wq16, Wk16, Wv16, bq, bk, bv, Qw, Kw, Vtw);

    dim3 gattn((SQ + 127) / 128, NBATCH * NHEADS);  // (11, 128)
    attn_kernel<<<gattn, 256, 0, stream>>>(Qw, Kw, Vtw, out);
}